// Round 1
// baseline (239.779 us; speedup 1.0000x reference)
//
#include <hip/hip_runtime.h>

// CTC loss forward. logits (T,N,C) fp32 log-probs, labels (N,S) int32 in
// [1,C), prediction/target sizes (N,).
//
// R8 restructure: two-phase. The R7 single-wave global_load_lds row staging
// (1KB LDS-DMA per t-row, one wave per CU) is ~10x off the HBM roofline --
// the lone wave's LDS-fill path is the ceiling, and there are no co-resident
// waves to hide it. Phase 1 (throughput kernel, 16 waves/CU) streams the
// full logits tensor once, gathers the 48 label columns + blank per (t,n)
// row, bakes in exp(lp + BOOST), and writes a compacted (T,N,64) fp32
// workspace. Phase 2 (the serial alpha chain, one wave per batch item) then
// consumes one coalesced 256B register load per step -- no LDS, no LDS-DMA,
// no transcendentals on the critical wave -- with a 40-row statically-
// indexed register prefetch pipeline (compiler-tracked vmcnt).
//
// Alpha tracked in LINEAR space: add/fma/mul chain, cross-lane dep per step
// = one DPP wave_shr1, wave-uniform renorm every 16 steps (DPP-max
// butterfly, logged into logscale). Emissions carry a +BOOST/step boost,
// un-done once at the end; validity masks folded into emissions.
//
// Workspace layout: ws[0..255] = per-item losses; ws+256 = comp (32 MB).

constexpr int T = 512, N = 256, C = 256, S = 48;
constexpr int G  = 8;                  // steps per group
constexpr int PF = 5;                  // prefetch depth in groups (40 rows)
constexpr int CW = 64;                 // compact row width (48 labels + blank x16)
constexpr float BOOST = 4.0f;          // per-live-step emission boost (e^4)
constexpr int TCHUNK = 16;             // phase-1 t-rows per block
static_assert((T - 1) == 63 * G + 7, "schedule hardcodes 63 groups + 7 epilogue");

__device__ __forceinline__ float wave_shr1(float v, float fill) {
  int r = __builtin_amdgcn_update_dpp(__float_as_int(fill), __float_as_int(v),
                                      0x138, 0xf, 0xf, false);  // wave_shr1
  return __int_as_float(r);
}

#define DPP_MAX(v, ctrl)                                                     \
  fmaxf(v, __int_as_float(__builtin_amdgcn_update_dpp(                       \
               __float_as_int(v), __float_as_int(v), (ctrl), 0xf, 0xf, false)))

// max over 64 lanes, wave-uniform result (alpha >= 0, old-value fallback on
// bcast-inactive lanes is safe).
__device__ __forceinline__ float wavemax(float v) {
  v = DPP_MAX(v, 0x111);               // row_shr:1
  v = DPP_MAX(v, 0x112);               // row_shr:2
  v = DPP_MAX(v, 0x114);               // row_shr:4
  v = DPP_MAX(v, 0x118);               // row_shr:8
  v = DPP_MAX(v, 0x142);               // row_bcast:15
  v = DPP_MAX(v, 0x143);               // row_bcast:31 -> lane 63 = full max
  return __int_as_float(__builtin_amdgcn_readlane(__float_as_int(v), 63));
}

// ---------------------------------------------------------------------------
// Phase 1: gather + exp compaction.
// comp[t][n][i] = exp(lp[t][n][sel_i] + BOOST),
//   sel_i = labels[n][i] for i < 48, blank (col 0) for i in [48,64).
// Each wave stages one full 1KB row to its private LDS buffer (float4
// coalesced), gathers via one lane-indexed ds_read, writes 256B coalesced.
// Double-buffered LDS per wave so consecutive iterations overlap.
// ---------------------------------------------------------------------------
__launch_bounds__(256)
__global__ void ctc_gather_kernel(const float* __restrict__ lp,
                                  const int*  __restrict__ labels,
                                  float* __restrict__ comp) {
  __shared__ float rows[4][2][C];      // 4 waves x double buffer x 1KB = 8KB
  const int lane = threadIdx.x & 63;
  const int w    = threadIdx.x >> 6;
  const int n    = blockIdx.y;
  const int col  = (lane < S) ? labels[n * S + lane] : 0;  // blank for 48..63
  const int tbase = blockIdx.x * TCHUNK;

#pragma unroll
  for (int i = 0; i < TCHUNK / 4; ++i) {
    const int t = tbase + w + i * 4;
    float (&buf)[C] = rows[w][i & 1];
    const float4 v = *reinterpret_cast<const float4*>(
        lp + ((size_t)t * N + n) * C + lane * 4);
    *reinterpret_cast<float4*>(&buf[lane * 4]) = v;
    const float g = buf[col];          // same-wave ds_write->ds_read, no barrier
    comp[((size_t)t * N + n) * CW + lane] = __expf(g + BOOST);
  }
}

// ---------------------------------------------------------------------------
// Phase 2: serial alpha chain, one 64-lane wave per batch item n.
// Lane i owns extended-lattice positions 2i (blank) and 2i+1 (label i).
// Per step: one coalesced 256B load of the compact row (pipelined PF groups
// ahead in registers, all indices static), readlane broadcast of the blank
// emission, two cndmask masks, and the 5-op linear-space update.
// ---------------------------------------------------------------------------
__launch_bounds__(64, 1)
__global__ void ctc_alpha_kernel(const float* __restrict__ lp,
                                 const float* __restrict__ comp,
                                 const int*  __restrict__ labels,
                                 const int*  __restrict__ in_len,
                                 const int*  __restrict__ tgt_len,
                                 float* __restrict__ loss_ws) {
  const int n    = blockIdx.x;
  const int lane = threadIdx.x;

  const int lab      = (lane < S) ? labels[n * S + lane] : 0;
  const int lab_prev = __shfl_up(lab, 1);
  const bool skip   = (lab != 0) && ((lane == 0) || (lab != lab_prev));
  const float skipf = skip ? 1.0f : 0.0f;
  const bool valid0 = (lane <= S);     // pos 2i     in [0, 2S]
  const bool valid1 = (lane <  S);     // pos 2i + 1 in [0, 2S]
  const int Tin = in_len[n];
  const int tl  = tgt_len[n];

  const float* nbase = lp + (size_t)n * C;             // lp[0][n][:]
  const float* cbase = comp + (size_t)n * CW + lane;   // comp[.][n][lane]
  constexpr size_t cstride = (size_t)N * CW;

  auto loadrow = [&](int t) -> float {
    const int rr = (t < T) ? t : (T - 1);              // clamped, never consumed
    return cbase[(size_t)rr * cstride];
  };
  // compact value -> masked (eb, el); emissions already exp'd + boosted.
  auto convert = [&](float v, float& eb, float& el) {
    const float blank = __int_as_float(
        __builtin_amdgcn_readlane(__float_as_int(v), 63));
    eb = valid0 ? blank : 0.0f;
    el = valid1 ? v : 0.0f;
  };

  // alpha0 in linear space (no boost at t=0): only lane 0 live.
  float a0 = (lane == 0) ? __expf(nbase[0])   : 0.0f;
  float a1 = (lane == 0) ? __expf(nbase[lab]) : 0.0f;
  float logscale = 0.0f;

  // Register prefetch pipeline: rows 1..PF*G in flight.
  float pf[PF][G];
#pragma unroll
  for (int p = 0; p < PF; ++p)
#pragma unroll
    for (int d = 0; d < G; ++d) pf[p][d] = loadrow(1 + p * G + d);

  int t0 = 1;
#pragma unroll 1
  for (int g = 0; g < 63; ++g, t0 += G) {
    // issue next group's loads first (PF groups ahead)
    float nv[G];
#pragma unroll
    for (int d = 0; d < G; ++d) nv[d] = loadrow(t0 + PF * G + d);

    float eb[G], el[G];
#pragma unroll
    for (int d = 0; d < G; ++d) convert(pf[0][d], eb[d], el[d]);

    if (t0 + G <= Tin) {                         // fast path: all 8 live
#pragma unroll
      for (int d = 0; d < G; ++d) {
        const float a1p = wave_shr1(a1, 0.0f);
        const float u   = a1 + a0;               // off the DPP dependency
        a0 = (a0 + a1p) * eb[d];
        a1 = fmaf(a1p, skipf, u) * el[d];
      }
    } else {                                     // tail: per-step freeze
#pragma unroll
      for (int d = 0; d < G; ++d) {
        const float a1p = wave_shr1(a1, 0.0f);
        const float u   = a1 + a0;
        const float na0 = (a0 + a1p) * eb[d];
        const float na1 = fmaf(a1p, skipf, u) * el[d];
        if (t0 + d < Tin) { a0 = na0; a1 = na1; }
      }
    }
    if (g & 1) {                                 // renorm every 16 steps
      float m = fmaxf(wavemax(fmaxf(a0, a1)), 1e-30f);
      const float inv = __builtin_amdgcn_rcpf(m);
      a0 *= inv; a1 *= inv;
      logscale -= __logf(inv);                   // log exactly what we applied
    }
    // rotate pipeline (register renames, all static indices)
#pragma unroll
    for (int p = 0; p < PF - 1; ++p)
#pragma unroll
      for (int d = 0; d < G; ++d) pf[p][d] = pf[p + 1][d];
#pragma unroll
    for (int d = 0; d < G; ++d) pf[PF - 1][d] = nv[d];
  }

  // Epilogue: t = 505..511 in pf[0][0..6] (pf[0][7] = clamped row 512).
#pragma unroll
  for (int d = 0; d < 7; ++d) {
    float eb, el;
    convert(pf[0][d], eb, el);
    const float a1p = wave_shr1(a1, 0.0f);
    const float u   = a1 + a0;
    const float na0 = (a0 + a1p) * eb;
    const float na1 = fmaf(a1p, skipf, u) * el;
    if (t0 + d < Tin) { a0 = na0; a1 = na1; }
  }

  // tails: alpha[2*tl-1] (lane tl-1, odd slot), alpha[2*tl] (lane tl, even)
  const float tail1 = __shfl(a1, tl - 1);
  const float tail2 = __shfl(a0, tl);
  if (lane == 0) {
    const int live = ((Tin < T) ? Tin : T) - 1;  // boosted live steps
    float loss = -(__logf(tail1 + tail2) + logscale - BOOST * (float)live);
    if (!(loss <= 1e29f) || isnan(loss)) loss = 0.0f;  // zero_infinity
    loss_ws[n] = loss / (float)tl;
  }
}

__launch_bounds__(256)
__global__ void ctc_reduce_kernel(const float* __restrict__ loss_ws,
                                  float* __restrict__ out) {
  const int tid = threadIdx.x;
  float v = loss_ws[tid];
#pragma unroll
  for (int off = 32; off > 0; off >>= 1) v += __shfl_down(v, off);
  __shared__ float partial[4];
  if ((tid & 63) == 0) partial[tid >> 6] = v;
  __syncthreads();
  if (tid == 0) {
    float s = (partial[0] + partial[1] + partial[2] + partial[3]) / (float)N;
    if (isnan(s) || isinf(s)) s = 0.0f;          // final sanitize()
    out[0] = s;
  }
}

extern "C" void kernel_launch(void* const* d_in, const int* in_sizes, int n_in,
                              void* d_out, int out_size, void* d_ws, size_t ws_size,
                              hipStream_t stream) {
  const float* lp     = (const float*)d_in[0];   // (T, N, C) fp32
  const int*   labels = (const int*)d_in[1];     // (N, S)
  const int*   plen   = (const int*)d_in[2];     // (N,)
  const int*   tlen   = (const int*)d_in[3];     // (N,)
  float* ws      = (float*)d_ws;
  float* loss_ws = ws;                           // N floats
  float* comp    = ws + 256;                     // (T, N, 64) fp32 = 32 MB
  float* out     = (float*)d_out;                // scalar

  dim3 ggrid(T / TCHUNK, N);
  ctc_gather_kernel<<<ggrid, 256, 0, stream>>>(lp, labels, comp);
  ctc_alpha_kernel<<<N, 64, 0, stream>>>(lp, comp, labels, plen, tlen, loss_ws);
  ctc_reduce_kernel<<<1, 256, 0, stream>>>(loss_ws, out);
}

// Round 2
// 218.854 us; speedup vs baseline: 1.0956x; 1.0956x over previous
//
#include <hip/hip_runtime.h>

// CTC loss forward. logits (T,N,C) fp32 log-probs, labels (N,S) int32 in
// [1,C), prediction/target sizes (N,).
//
// R9: two-phase (gather/compact + serial alpha), pipeline repairs.
// R8 post-mortem: dur 239.8us; top-5 dispatches are all 512MiB ws-poison
// fills (~78us) -> every kernel of ours is <76.7us, so at least one of
// gather/alpha ran ~70us, way off roofline. Two pipeline bugs suspected:
//  (a) alpha's rotating register pipeline (pf[p]=pf[p+1]) copies pending
//      load targets -> compiler drains vmcnt every iteration -> 40-deep
//      pipeline collapses to ~1 group in flight;
//  (b) gather's 2-buffer LDS reuse serializes iterations 2,3 on 0,1.
// Fixes: alpha uses two statically-named 16-row register buffers with
// unroll-by-2 modulo scheduling (zero copies, 32 loads in flight), comp
// re-laid-out as (N,T,64) so each alpha wave streams a contiguous 128KB
// slice; comp over-allocated by one row so no per-load clamp. Gather uses
// 4 independent LDS buffers per wave.
//
// Alpha tracked in LINEAR space: add/fma/mul chain, cross-lane dep per step
// = one DPP wave_shr1, wave-uniform renorm every 16 steps (DPP-max
// butterfly, logged into logscale). Emissions carry a +BOOST/step boost
// (un-done once at the end); validity masks folded into emissions.
//
// Workspace: ws[0..255] per-item losses; ws+256 = comp (N,T,64)+1 row.

constexpr int T = 512, N = 256, C = 256, S = 48;
constexpr int GG = 16;                 // steps per register buffer
constexpr int CW = 64;                 // compact row width (48 labels + blank x16)
constexpr float BOOST = 4.0f;          // per-live-step emission boost (e^4)
constexpr int TCHUNK = 16;             // phase-1 t-rows per block
static_assert((T - 1) == 15 * 2 * GG + GG + (GG - 1), "schedule: 15x2 groups + 16 + 15");

__device__ __forceinline__ float wave_shr1(float v, float fill) {
  int r = __builtin_amdgcn_update_dpp(__float_as_int(fill), __float_as_int(v),
                                      0x138, 0xf, 0xf, false);  // wave_shr1
  return __int_as_float(r);
}

#define DPP_MAX(v, ctrl)                                                     \
  fmaxf(v, __int_as_float(__builtin_amdgcn_update_dpp(                       \
               __float_as_int(v), __float_as_int(v), (ctrl), 0xf, 0xf, false)))

// max over 64 lanes, wave-uniform result (alpha >= 0, old-value fallback on
// bcast-inactive lanes is safe).
__device__ __forceinline__ float wavemax(float v) {
  v = DPP_MAX(v, 0x111);               // row_shr:1
  v = DPP_MAX(v, 0x112);               // row_shr:2
  v = DPP_MAX(v, 0x114);               // row_shr:4
  v = DPP_MAX(v, 0x118);               // row_shr:8
  v = DPP_MAX(v, 0x142);               // row_bcast:15
  v = DPP_MAX(v, 0x143);               // row_bcast:31 -> lane 63 = full max
  return __int_as_float(__builtin_amdgcn_readlane(__float_as_int(v), 63));
}

// ---------------------------------------------------------------------------
// Phase 1: gather + exp compaction.
// comp[n][t][i] = exp(lp[t][n][sel_i] + BOOST),
//   sel_i = labels[n][i] for i < 48, blank (col 0) for i in [48,64).
// Each wave stages one full 1KB row to a PRIVATE LDS buffer (float4
// coalesced), gathers via one lane-indexed ds_read (~2-4 way bank alias,
// cheap), writes 256B coalesced. 4 independent buffers per wave -> all 4
// global loads in flight at once; 16 waves/CU of TLP on top.
// ---------------------------------------------------------------------------
__launch_bounds__(256)
__global__ void ctc_gather_kernel(const float* __restrict__ lp,
                                  const int*  __restrict__ labels,
                                  float* __restrict__ comp) {
  __shared__ float rows[4][4][C];      // 4 waves x 4 buffers x 1KB = 16 KB
  const int lane = threadIdx.x & 63;
  const int w    = threadIdx.x >> 6;
  const int n    = blockIdx.y;
  const int col  = (lane < S) ? labels[n * S + lane] : 0;  // blank for 48..63
  const int tbase = blockIdx.x * TCHUNK;

#pragma unroll
  for (int i = 0; i < 4; ++i) {
    const int t = tbase + w + i * 4;
    float (&buf)[C] = rows[w][i];
    const float4 v = *reinterpret_cast<const float4*>(
        lp + ((size_t)t * N + n) * C + lane * 4);
    *reinterpret_cast<float4*>(&buf[lane * 4]) = v;
    const float g = buf[col];          // same-wave ds_write->ds_read
    comp[((size_t)n * T + t) * CW + lane] = __expf(g + BOOST);
  }
}

// ---------------------------------------------------------------------------
// Phase 2: serial alpha chain, one 64-lane wave per batch item n.
// Lane i owns extended-lattice positions 2i (blank) and 2i+1 (label i).
// Per step: one coalesced 256B register load (two statically-named 16-row
// buffers, unroll-by-2 modulo schedule -> no register copies, 32 loads in
// flight, compiler-tracked vmcnt(16) per phase), readlane broadcast of the
// blank emission, two cndmasks, and the 5-op linear-space update.
// ---------------------------------------------------------------------------
__launch_bounds__(64, 1)
__global__ void ctc_alpha_kernel(const float* __restrict__ lp,
                                 const float* __restrict__ comp,
                                 const int*  __restrict__ labels,
                                 const int*  __restrict__ in_len,
                                 const int*  __restrict__ tgt_len,
                                 float* __restrict__ loss_ws) {
  const int n    = blockIdx.x;
  const int lane = threadIdx.x;

  const int lab      = (lane < S) ? labels[n * S + lane] : 0;
  const int lab_prev = __shfl_up(lab, 1);
  const bool skip   = (lab != 0) && ((lane == 0) || (lab != lab_prev));
  const float skipf = skip ? 1.0f : 0.0f;
  const bool valid0 = (lane <= S);     // pos 2i     in [0, 2S]
  const bool valid1 = (lane <  S);     // pos 2i + 1 in [0, 2S]
  const int Tin = in_len[n];
  const int tl  = tgt_len[n];

  const float* nbase = lp + (size_t)n * C;                   // lp[0][n][:]
  const float* cbase = comp + ((size_t)n * T) * CW + lane;   // comp[n][.][lane]

  // row t of this n's compact slice; comp has one spare row past the end,
  // so t = T is a safe (never-consumed) prefetch.
  auto loadrow = [&](int t) -> float { return cbase[(size_t)t * CW]; };

  // alpha0 in linear space (no boost at t=0): only lane 0 live.
  float a0 = (lane == 0) ? __expf(nbase[0])   : 0.0f;
  float a1 = (lane == 0) ? __expf(nbase[lab]) : 0.0f;
  float logscale = 0.0f;

  // Prologue: A = rows 1..16, B = rows 17..32 in flight.
  float A[GG], B[GG];
#pragma unroll
  for (int d = 0; d < GG; ++d) A[d] = loadrow(1 + d);
#pragma unroll
  for (int d = 0; d < GG; ++d) B[d] = loadrow(1 + GG + d);

  // One phase: convert buffer -> (eb,el), refill buffer (loads land 2 phases
  // later), run 16 chain steps, renorm. All indices static.
#define PHASE(BUF, TB, DOREFILL, RB)                                         \
  {                                                                          \
    float eb[GG], el[GG];                                                    \
    _Pragma("unroll")                                                        \
    for (int d = 0; d < GG; ++d) {                                           \
      const float v = BUF[d];                                                \
      const float blank = __int_as_float(                                    \
          __builtin_amdgcn_readlane(__float_as_int(v), 63));                 \
      eb[d] = valid0 ? blank : 0.0f;                                         \
      el[d] = valid1 ? v : 0.0f;                                             \
    }                                                                        \
    if (DOREFILL) {                                                          \
      _Pragma("unroll")                                                      \
      for (int d = 0; d < GG; ++d) BUF[d] = loadrow((RB) + d);               \
    }                                                                        \
    if ((TB) + GG <= Tin) {                                                  \
      _Pragma("unroll")                                                      \
      for (int d = 0; d < GG; ++d) {                                         \
        const float a1p = wave_shr1(a1, 0.0f);                               \
        const float u   = a1 + a0;        /* off the DPP dependency */       \
        a0 = (a0 + a1p) * eb[d];                                             \
        a1 = fmaf(a1p, skipf, u) * el[d];                                    \
      }                                                                      \
    } else {                                                                 \
      _Pragma("unroll")                                                      \
      for (int d = 0; d < GG; ++d) {                                         \
        const float a1p = wave_shr1(a1, 0.0f);                               \
        const float u   = a1 + a0;                                           \
        const float na0 = (a0 + a1p) * eb[d];                                \
        const float na1 = fmaf(a1p, skipf, u) * el[d];                       \
        if ((TB) + d < Tin) { a0 = na0; a1 = na1; }                          \
      }                                                                      \
    }                                                                        \
    float m = fmaxf(wavemax(fmaxf(a0, a1)), 1e-30f);                         \
    const float inv = __builtin_amdgcn_rcpf(m);                              \
    a0 *= inv; a1 *= inv;                                                    \
    logscale -= __logf(inv);             /* log exactly what we applied */   \
  }

  int t0 = 1;
#pragma unroll 1
  for (int gg = 0; gg < 15; ++gg, t0 += 2 * GG) {
    PHASE(A, t0,      true, t0 + 2 * GG);          // consume A, refill A
    PHASE(B, t0 + GG, true, t0 + 3 * GG);          // consume B, refill B
  }

  // Epilogue: t0 = 481. A holds rows 481..496, B holds 497..512.
  PHASE(A, t0, false, 0);                          // t = 481..496
  {                                                // t = 497..511 (15 steps)
    float eb[GG], el[GG];
#pragma unroll
    for (int d = 0; d < GG - 1; ++d) {
      const float v = B[d];
      const float blank = __int_as_float(
          __builtin_amdgcn_readlane(__float_as_int(v), 63));
      eb[d] = valid0 ? blank : 0.0f;
      el[d] = valid1 ? v : 0.0f;
    }
#pragma unroll
    for (int d = 0; d < GG - 1; ++d) {
      const float a1p = wave_shr1(a1, 0.0f);
      const float u   = a1 + a0;
      const float na0 = (a0 + a1p) * eb[d];
      const float na1 = fmaf(a1p, skipf, u) * el[d];
      if (t0 + GG + d < Tin) { a0 = na0; a1 = na1; }
    }
  }
#undef PHASE

  // tails: alpha[2*tl-1] (lane tl-1, odd slot), alpha[2*tl] (lane tl, even)
  const float tail1 = __shfl(a1, tl - 1);
  const float tail2 = __shfl(a0, tl);
  if (lane == 0) {
    const int live = ((Tin < T) ? Tin : T) - 1;    // boosted live steps
    float loss = -(__logf(tail1 + tail2) + logscale - BOOST * (float)live);
    if (!(loss <= 1e29f) || isnan(loss)) loss = 0.0f;  // zero_infinity
    loss_ws[n] = loss / (float)tl;
  }
}

__launch_bounds__(256)
__global__ void ctc_reduce_kernel(const float* __restrict__ loss_ws,
                                  float* __restrict__ out) {
  const int tid = threadIdx.x;
  float v = loss_ws[tid];
#pragma unroll
  for (int off = 32; off > 0; off >>= 1) v += __shfl_down(v, off);
  __shared__ float partial[4];
  if ((tid & 63) == 0) partial[tid >> 6] = v;
  __syncthreads();
  if (tid == 0) {
    float s = (partial[0] + partial[1] + partial[2] + partial[3]) / (float)N;
    if (isnan(s) || isinf(s)) s = 0.0f;            // final sanitize()
    out[0] = s;
  }
}

extern "C" void kernel_launch(void* const* d_in, const int* in_sizes, int n_in,
                              void* d_out, int out_size, void* d_ws, size_t ws_size,
                              hipStream_t stream) {
  const float* lp     = (const float*)d_in[0];     // (T, N, C) fp32
  const int*   labels = (const int*)d_in[1];       // (N, S)
  const int*   plen   = (const int*)d_in[2];       // (N,)
  const int*   tlen   = (const int*)d_in[3];       // (N,)
  float* ws      = (float*)d_ws;
  float* loss_ws = ws;                             // N floats
  float* comp    = ws + 256;                       // (N, T, 64) fp32 + 1 row
  float* out     = (float*)d_out;                  // scalar

  dim3 ggrid(T / TCHUNK, N);
  ctc_gather_kernel<<<ggrid, 256, 0, stream>>>(lp, labels, comp);
  ctc_alpha_kernel<<<N, 64, 0, stream>>>(lp, comp, labels, plen, tlen, loss_ws);
  ctc_reduce_kernel<<<1, 256, 0, stream>>>(loss_ws, out);
}